// Round 15
// baseline (458.492 us; speedup 1.0000x reference)
//
#include <hip/hip_runtime.h>

// Problem constants: B=4, S=2048, D=1024, H=16, HD=64
#define S_LEN 2048
#define NH 16
#define HDIM 64
#define DMODEL 1024

typedef __attribute__((ext_vector_type(8))) short bf16x8;
typedef __attribute__((ext_vector_type(4))) float f32x4;

__device__ __forceinline__ short f2bf(float f) {
    union { float f; unsigned u; } x; x.f = f;
    unsigned r = x.u + 0x7fffu + ((x.u >> 16) & 1u);  // round-to-nearest-even
    return (short)(r >> 16);
}

#define GLDS(g, l) __builtin_amdgcn_global_load_lds( \
    (__attribute__((address_space(1))) void*)(g),    \
    (__attribute__((address_space(3))) void*)(l), 16, 0, 0)

#define QSCALE 0.18033688011112042f   // 0.125 * log2(e)
#define FREQ_L 0.41524101186109327f   // log2(10000)/32

// ---------------------------------------------------------------- prep (one launch)
__global__ __launch_bounds__(256) void prep(const float* __restrict__ x,
                                            const float* __restrict__ wq,
                                            const float* __restrict__ wk,
                                            const float* __restrict__ wv,
                                            const float* __restrict__ wo,
                                            const int* __restrict__ tp,
                                            short* __restrict__ xb,
                                            short* __restrict__ wqb,
                                            short* __restrict__ wkb,
                                            short* __restrict__ wvb,
                                            short* __restrict__ wob,
                                            float2* __restrict__ tab) {
    int bid = blockIdx.x;
    if (bid < 8192) {
        int i = bid * 256 + threadIdx.x;
        float4 v = ((const float4*)x)[i];
        short4 o;
        o.x = f2bf(v.x); o.y = f2bf(v.y); o.z = f2bf(v.z); o.w = f2bf(v.w);
        ((short4*)xb)[i] = o;
    } else if (bid < 12288) {
        int sel = (bid - 8192) >> 10;
        const float* in = sel == 0 ? wq : sel == 1 ? wk : sel == 2 ? wv : wo;
        short* out = sel == 0 ? wqb : sel == 1 ? wkb : sel == 2 ? wvb : wob;
        int i = ((bid - 8192) & 1023) * 256 + threadIdx.x;
        float4 v = ((const float4*)in)[i];
        short4 o;
        o.x = f2bf(v.x); o.y = f2bf(v.y); o.z = f2bf(v.z); o.w = f2bf(v.w);
        ((short4*)out)[i] = o;
    } else {
        int idx = (bid - 12288) * 256 + threadIdx.x;   // < 262144
        int b = idx >> 16, s = (idx >> 5) & 2047, i = idx & 31;
        float p = (float)tp[(b << 11) + s];
        float freq = exp2f(-(float)i * FREQ_L);
        float sn, cs;
        sincosf(p * freq, &sn, &cs);
        tab[idx] = make_float2(cs, sn);
    }
}

// ---------------------------------------------------------------- fused QKV GEMM + RoPE
// Round-12 version KEPT (66.0 us, Occ 32%, FETCH 45 MB).  2-blocks/CU
// counted-vmcnt schedule: BK=32/phase (32 phases), 3 slots x 24 KB = 72 KB
// LDS; vmcnt(3) steady (never drain).  (row>>1)&3 conflict-free addressing.
// XCD grid (32,24), bm fastest.  BM=256, BN=128; 8 waves (4Mx2N).
__global__ __launch_bounds__(512) void gemm_qkv(const short* __restrict__ A,
                                                const short* __restrict__ Bq,
                                                const short* __restrict__ Bk,
                                                const short* __restrict__ Bv,
                                                const float2* __restrict__ tab,
                                                short* __restrict__ Qo,
                                                short* __restrict__ Ko,
                                                short* __restrict__ Vo) {
    constexpr int K = 1024;
    __shared__ __align__(16) short smem[3 * 12288];

    const int bm = blockIdx.x;               // 0..31  (fastest -> XCD-pinned A)
    const int sel = blockIdx.y >> 3;         // 0..2
    const int bn = blockIdx.y & 7;           // 0..7
    const short* Bm = sel == 0 ? Bq : sel == 1 ? Bk : Bv;
    short* Cb = sel == 0 ? Qo : sel == 1 ? Ko : Vo;

    const int tid = threadIdx.x;
    const int lane = tid & 63;
    const int w = tid >> 6;          // 0..7
    const int wm = w >> 1;           // 0..3  (M-waves)
    const int wn = w & 1;            // 0..1  (N-waves)
    const int quad = lane >> 4, l16 = lane & 15;

    int aoff[2], boffv;
#pragma unroll
    for (int i = 0; i < 2; i++) {
        int Lc = i * 512 + tid;
        int row = Lc >> 2;
        int gc = (Lc & 3) ^ ((row >> 1) & 3);
        aoff[i] = (bm * 256 + row) * K + gc * 8;
    }
    {
        int row = tid >> 2;
        int gc = (tid & 3) ^ ((row >> 1) & 3);
        boffv = (bn * 128 + row) * K + gc * 8;
    }

    auto stage = [&](int h, int slot) {
        char* sbase = (char*)smem + slot * 24576;
        const int kh = h * 32;
#pragma unroll
        for (int i = 0; i < 2; i++)
            GLDS(A + aoff[i] + kh, sbase + i * 8192 + w * 1024);
        GLDS(Bm + boffv + kh, sbase + 16384 + w * 1024);
    };

    f32x4 acc[4][4] = {};
    const int rsw = (quad ^ ((l16 >> 1) & 3)) * 8;

    auto compute = [&](int slot) {
        const short* sA = smem + slot * 12288;
        const short* sB = sA + 8192;
        bf16x8 af[4], bfm[4];
#pragma unroll
        for (int mi = 0; mi < 4; mi++)
            af[mi] = *(const bf16x8*)&sA[(wm * 64 + mi * 16 + l16) * 32 + rsw];
#pragma unroll
        for (int ni = 0; ni < 4; ni++)
            bfm[ni] = *(const bf16x8*)&sB[(wn * 64 + ni * 16 + l16) * 32 + rsw];
        __builtin_amdgcn_s_setprio(1);
#pragma unroll
        for (int mi = 0; mi < 4; mi++)
#pragma unroll
            for (int ni = 0; ni < 4; ni++)
                acc[mi][ni] = __builtin_amdgcn_mfma_f32_16x16x32_bf16(af[mi], bfm[ni],
                                                                      acc[mi][ni], 0, 0, 0);
        __builtin_amdgcn_s_setprio(0);
    };

    stage(0, 0); stage(1, 1);

    auto step = [&](int h, int sc, int ss) {
        asm volatile("s_waitcnt vmcnt(3)" ::: "memory");   // tile h complete
        __builtin_amdgcn_s_barrier();
        __builtin_amdgcn_sched_barrier(0);
        stage(h + 2, ss);
        compute(sc);
    };

    for (int h = 0; h < 30; h += 3) {
        step(h + 0, 0, 2);
        step(h + 1, 1, 0);
        step(h + 2, 2, 1);
    }
    asm volatile("s_waitcnt vmcnt(3)" ::: "memory");
    __builtin_amdgcn_s_barrier();
    __builtin_amdgcn_sched_barrier(0);
    compute(0);
    asm volatile("s_waitcnt vmcnt(0)" ::: "memory");
    __builtin_amdgcn_s_barrier();
    __builtin_amdgcn_sched_barrier(0);
    compute(1);

    const int gm0 = bm * 256 + wm * 64;
    const int gn0 = bn * 128 + wn * 64;

    if (sel == 2) {
        // ---- V^T -> [B][H][64][S] via LDS transpose (re-use staging LDS).
        short* T = smem;
        __syncthreads();
#pragma unroll
        for (int mi = 0; mi < 4; mi++) {
            int lmb = wm * 64 + mi * 16 + quad * 4;
#pragma unroll
            for (int ni = 0; ni < 4; ni++) {
                int ln = wn * 64 + ni * 16 + l16;
                short4 pk;
                pk.x = f2bf(acc[mi][ni][0]);
                pk.y = f2bf(acc[mi][ni][1]);
                pk.z = f2bf(acc[mi][ni][2]);
                pk.w = f2bf(acc[mi][ni][3]);
                *(short4*)&T[ln * 256 + (lmb ^ ((ln & 31) << 3))] = pk;
            }
        }
        __syncthreads();
        const int row = tid >> 2, qt = tid & 3;
        const int grow = bn * 128 + row;
        const int gb = bm >> 3;
        const int gs0 = (bm & 7) * 256;
        short* dst = Cb + (((size_t)(gb * NH + (grow >> 6)) * HDIM + (grow & 63)) * S_LEN
                           + gs0 + qt * 64);
#pragma unroll
        for (int j = 0; j < 8; j++) {
            bf16x8 v = *(const bf16x8*)&T[row * 256 +
                        ((qt * 64 + j * 8) ^ ((row & 31) << 3))];
            *(bf16x8*)(dst + j * 8) = v;
        }
    } else {
        const float qs = (sel == 0) ? QSCALE : 1.0f;
#pragma unroll
        for (int mi = 0; mi < 4; mi++)
#pragma unroll
            for (int r = 0; r < 4; r++) {
                int gm = gm0 + mi * 16 + quad * 4 + r;        // b*2048 + s
                const float2* trow = tab + (gm << 5);
                int b = gm >> 11, s = gm & 2047;
#pragma unroll
                for (int ni = 0; ni < 4; ni++) {
                    float2 cs = trow[ni * 8 + (l16 >> 1)];
                    float v = acc[mi][ni][r];
                    float prt = __shfl_xor(v, 1, 64);
                    float val = (l16 & 1) ? (prt * cs.y + v * cs.x)
                                          : (v * cs.x - prt * cs.y);
                    int gn = gn0 + ni * 16 + l16;
                    int h = gn >> 6, hd = gn & 63;
                    Cb[((b * NH + h) * S_LEN + s) * HDIM + hd] = f2bf(val * qs);
                }
            }
    }
}

// ---------------------------------------------------------------- O-projection GEMM
// Round-13 version KEPT (2-blocks/CU: BM=128/BN=128/BK=32, 48 KB LDS,
// vmcnt(2), (row>>1)&3 addressing, grid (64,8) XCD-pinned).
__global__ __launch_bounds__(512) void gemm_o(const short* __restrict__ A,
                                              const short* __restrict__ Bw,
                                              float* __restrict__ Cf) {
    constexpr int K = 1024, N = 1024;
    __shared__ __align__(16) short smem[3 * 8192];

    const int bm = blockIdx.x;       // 0..63  (fastest -> XCD-pinned A)
    const int bn = blockIdx.y;       // 0..7

    const int tid = threadIdx.x;
    const int lane = tid & 63;
    const int w = tid >> 6;          // 0..7
    const int wm = w >> 2;           // 0..1  (M-waves)
    const int wn = w & 3;            // 0..3  (N-waves)
    const int quad = lane >> 4, l16 = lane & 15;

    int aoffv, boffv;
    {
        int row = tid >> 2;
        int gc = (tid & 3) ^ ((row >> 1) & 3);
        aoffv = (bm * 128 + row) * K + gc * 8;
        boffv = (bn * 128 + row) * K + gc * 8;
    }

    auto stage = [&](int h, int slot) {
        char* sbase = (char*)smem + slot * 16384;
        const int kh = h * 32;
        GLDS(A + aoffv + kh, sbase + w * 1024);
        GLDS(Bw + boffv + kh, sbase + 8192 + w * 1024);
    };

    f32x4 acc[4][2] = {};
    const int rsw = (quad ^ ((l16 >> 1) & 3)) * 8;

    auto compute = [&](int slot) {
        const short* sA = smem + slot * 8192;
        const short* sB = sA + 4096;
        bf16x8 af[4], bfm[2];
#pragma unroll
        for (int mi = 0; mi < 4; mi++)
            af[mi] = *(const bf16x8*)&sA[(wm * 64 + mi * 16 + l16) * 32 + rsw];
#pragma unroll
        for (int ni = 0; ni < 2; ni++)
            bfm[ni] = *(const bf16x8*)&sB[(wn * 32 + ni * 16 + l16) * 32 + rsw];
        __builtin_amdgcn_s_setprio(1);
#pragma unroll
        for (int mi = 0; mi < 4; mi++)
#pragma unroll
            for (int ni = 0; ni < 2; ni++)
                acc[mi][ni] = __builtin_amdgcn_mfma_f32_16x16x32_bf16(af[mi], bfm[ni],
                                                                      acc[mi][ni], 0, 0, 0);
        __builtin_amdgcn_s_setprio(0);
    };

    stage(0, 0); stage(1, 1);

    auto step = [&](int h, int sc, int ss) {
        asm volatile("s_waitcnt vmcnt(2)" ::: "memory");
        __builtin_amdgcn_s_barrier();
        __builtin_amdgcn_sched_barrier(0);
        stage(h + 2, ss);
        compute(sc);
    };

    for (int h = 0; h < 30; h += 3) {
        step(h + 0, 0, 2);
        step(h + 1, 1, 0);
        step(h + 2, 2, 1);
    }
    asm volatile("s_waitcnt vmcnt(2)" ::: "memory");
    __builtin_amdgcn_s_barrier();
    __builtin_amdgcn_sched_barrier(0);
    compute(0);
    asm volatile("s_waitcnt vmcnt(0)" ::: "memory");
    __builtin_amdgcn_s_barrier();
    __builtin_amdgcn_sched_barrier(0);
    compute(1);

    const int gm0 = bm * 128 + wm * 64;
    const int gn0 = bn * 128 + wn * 32;
#pragma unroll
    for (int mi = 0; mi < 4; mi++)
#pragma unroll
        for (int ni = 0; ni < 2; ni++)
#pragma unroll
            for (int r = 0; r < 4; r++) {
                int gm = gm0 + mi * 16 + quad * 4 + r;
                int gn = gn0 + ni * 16 + l16;
                Cf[gm * N + gn] = acc[mi][ni][r];
            }
}

// ---------------------------------------------------------------- flash attention (causal)
// Q,K: [BH][S][64] bf16 (Q pre-scaled by 0.125*log2e), Vt: [BH][64][S] bf16,
// O: [B][S][D] bf16.  Fixed-max softmax.
// Round-15: 5-BLOCKS/CU — trade prefetch for occupancy.  attn is a serial
// dependency chain; rounds 6-14 showed all pipes <35% busy at 2-3 waves/SIMD.
// Single-buffer K/V (8+8 KB) + pbuf 16 KB = 32 KB/block -> EXACTLY 5
// blocks/CU (160 KB) = 5 waves/SIMD.  The per-iter staging drain (canonical
// stage -> vmcnt(0) -> barrier) is now fully exposed per block but covered
// by 4 other co-resident blocks at different phases — the same TLP mechanism
// round 12 validated on gemm_qkv (Occ 19->32% -> -5.4 us).
// LPT grid kept from r14 (validated): (64,16), Qt = 15 - blockIdx.y (longest
// first), bh = blockIdx.x fastest (XCD-pinned K/V).  Body byte-identical to
// r14's measured-good loop.
__global__ __launch_bounds__(256, 5) void attn(const short* __restrict__ Q,
                                               const short* __restrict__ Km,
                                               const short* __restrict__ Vt,
                                               short* __restrict__ O) {
    __shared__ __align__(16) short kbuf[64 * 64];      // 8 KB (single buffer)
    __shared__ __align__(16) short vbuf[64 * 64];      // 8 KB (single buffer)
    __shared__ __align__(16) short pbuf[4][32 * 64];   // 16 KB (per-wave private)

    const int lane = threadIdx.x & 63;
    const int w = threadIdx.x >> 6;
    const int quad = lane >> 4, l16 = lane & 15;
    const int l7 = l16 & 7;
    const int bh = blockIdx.x;         // fastest -> XCD-pinned K/V

    const short* Qg = Q  + bh * S_LEN * 64;
    const short* Kg = Km + bh * S_LEN * 64;
    const short* Vg = Vt + bh * 64 * S_LEN;
    short* myp = &pbuf[w][0];

    const int b = bh >> 4, h = bh & 15;

    bf16x8 ones;
#pragma unroll
    for (int j = 0; j < 8; j++) ones[j] = (short)0x3f80;   // bf16 1.0

    auto stage = [&](int kt) {
        const short* kt_base = Kg + kt * 64 * 64;
        const short* vt_base = Vg + kt * 64;
#pragma unroll
        for (int i = 0; i < 2; ++i) {
            int ch = w * 128 + i * 64 + lane;
            int row = ch >> 3;
            int c = (ch & 7) ^ (row & 7);
            GLDS(kt_base + row * 64 + c * 8, (char*)&kbuf[(w * 128 + i * 64) * 8]);
        }
#pragma unroll
        for (int i = 0; i < 2; ++i) {
            int ch = w * 128 + i * 64 + lane;
            int row = ch >> 3;
            int c = (ch & 7) ^ (row & 7);
            GLDS(vt_base + row * S_LEN + c * 8, (char*)&vbuf[(w * 128 + i * 64) * 8]);
        }
    };

    const int Qt = 15 - blockIdx.y;    // LPT: longest blocks dispatch first
    const int nkt = 2 * Qt + 2;

    bf16x8 aq[2][2];
#pragma unroll
    for (int mi = 0; mi < 2; mi++) {
        int qrow = Qt * 128 + w * 32 + mi * 16 + l16;
#pragma unroll
        for (int kc = 0; kc < 2; kc++)
            aq[mi][kc] = *(const bf16x8*)&Qg[qrow * 64 + kc * 32 + quad * 8];
    }

    f32x4 oacc[2][4] = {};
    f32x4 lacc[2] = {};

    for (int kt = 0; kt < nkt; ++kt) {
        __syncthreads();   // all waves' reads of kbuf/vbuf from iter kt-1 done (WAR)
        stage(kt);
        asm volatile("s_waitcnt vmcnt(0)" ::: "memory");   // my stripes landed
        __syncthreads();                                   // everyone's stripes landed

        // ---- S = Q K^T  (independent chains: 2 mi x 4 nt)
        f32x4 sc[2][4] = {};
        __builtin_amdgcn_s_setprio(1);
#pragma unroll
        for (int nt = 0; nt < 4; nt++) {
            int raddr = (nt * 16 + l16) * 64;
#pragma unroll
            for (int kc = 0; kc < 2; kc++) {
                bf16x8 kf = *(const bf16x8*)&kbuf[raddr + (((quad + kc * 4) ^ l7) * 8)];
                sc[0][nt] = __builtin_amdgcn_mfma_f32_16x16x32_bf16(aq[0][kc], kf, sc[0][nt], 0, 0, 0);
                sc[1][nt] = __builtin_amdgcn_mfma_f32_16x16x32_bf16(aq[1][kc], kf, sc[1][nt], 0, 0, 0);
            }
        }
        __builtin_amdgcn_s_setprio(0);
        // ---- causal mask (only last two tiles hit the diagonal)
        if (kt >= nkt - 2) {
#pragma unroll
            for (int mi = 0; mi < 2; mi++)
#pragma unroll
                for (int nt = 0; nt < 4; nt++)
#pragma unroll
                    for (int r = 0; r < 4; r++) {
                        int col = kt * 64 + nt * 16 + l16;
                        int row = Qt * 128 + w * 32 + mi * 16 + quad * 4 + r;
                        if (col > row) sc[mi][nt][r] = -__builtin_inff();
                    }
        }
        // ---- p = exp2(s); truncated bf16 store (d16_hi, zero VALU convert)
#pragma unroll
        for (int mi = 0; mi < 2; mi++)
#pragma unroll
            for (int nt = 0; nt < 4; nt++)
#pragma unroll
                for (int r = 0; r < 4; r++) {
                    float pv = __builtin_amdgcn_exp2f(sc[mi][nt][r]);
                    int q = mi * 16 + quad * 4 + r;
                    union { float f; unsigned short us[2]; } uu;
                    uu.f = pv;
                    myp[q * 64 + (((nt * 2 + (l16 >> 3)) ^ (q & 7)) * 8) + l7] =
                        (short)uu.us[1];
                }
        // ---- P: LDS -> A-frags (in-wave DS ordering; no barrier needed)
        bf16x8 ap[2][2];
#pragma unroll
        for (int mi = 0; mi < 2; mi++)
#pragma unroll
            for (int kc = 0; kc < 2; kc++)
                ap[mi][kc] = *(const bf16x8*)&myp[(mi * 16 + l16) * 64 +
                                                  (((quad + kc * 4) ^ l7) * 8)];
        // ---- O += P V ; denominator += P * ones (MFMA pipe)
        __builtin_amdgcn_s_setprio(1);
#pragma unroll
        for (int nt = 0; nt < 4; nt++) {
            int raddr = (nt * 16 + l16) * 64;
#pragma unroll
            for (int kc = 0; kc < 2; kc++) {
                bf16x8 vf = *(const bf16x8*)&vbuf[raddr + (((quad + kc * 4) ^ l7) * 8)];
                oacc[0][nt] = __builtin_amdgcn_mfma_f32_16x16x32_bf16(ap[0][kc], vf, oacc[0][nt], 0, 0, 0);
                oacc[1][nt] = __builtin_amdgcn_mfma_f32_16x16x32_bf16(ap[1][kc], vf, oacc[1][nt], 0, 0, 0);
            }
        }
#pragma unroll
        for (int mi = 0; mi < 2; mi++) {
            lacc[mi] = __builtin_amdgcn_mfma_f32_16x16x32_bf16(ap[mi][0], ones, lacc[mi], 0, 0, 0);
            lacc[mi] = __builtin_amdgcn_mfma_f32_16x16x32_bf16(ap[mi][1], ones, lacc[mi], 0, 0, 0);
        }
        __builtin_amdgcn_s_setprio(0);
    }
    // ---- epilogue: lacc holds per-row denominators (all cols equal)
#pragma unroll
    for (int mi = 0; mi < 2; mi++)
#pragma unroll
        for (int r = 0; r < 4; r++) {
            float inv = 1.0f / lacc[mi][r];
            int srow = Qt * 128 + w * 32 + mi * 16 + quad * 4 + r;
#pragma unroll
            for (int nt = 0; nt < 4; nt++) {
                int hd = nt * 16 + l16;
                O[(b * S_LEN + srow) * DMODEL + h * HDIM + hd] = f2bf(oacc[mi][nt][r] * inv);
            }
        }
}

// ---------------------------------------------------------------- launch
extern "C" void kernel_launch(void* const* d_in, const int* in_sizes, int n_in,
                              void* d_out, int out_size, void* d_ws, size_t ws_size,
                              hipStream_t stream) {
    const float* x  = (const float*)d_in[0];
    const int*   tp = (const int*)d_in[1];
    const float* Wq = (const float*)d_in[2];
    const float* Wk = (const float*)d_in[3];
    const float* Wv = (const float*)d_in[4];
    const float* Wo = (const float*)d_in[5];
    float* out = (float*)d_out;

    char* ws = (char*)d_ws;
    const size_t MB = 1024 * 1024;
    short* xb  = (short*)(ws);             // 16 MB: x bf16 [8192][1024]; reused as o_buf
    short* wqb = (short*)(ws + 16 * MB);
    short* wkb = (short*)(ws + 18 * MB);
    short* wvb = (short*)(ws + 20 * MB);
    short* wob = (short*)(ws + 22 * MB);
    short* Qb  = (short*)(ws + 24 * MB);   // 16 MB [BH][S][64]
    short* Kb  = (short*)(ws + 40 * MB);   // 16 MB [BH][S][64]
    short* Vtb = (short*)(ws + 56 * MB);   // 16 MB [BH][64][S]
    // RoPE table (2 MB) lives in d_out: scratch until gemm_o overwrites it.
    float2* tab = (float2*)d_out;

    prep<<<13312, 256, 0, stream>>>(x, Wq, Wk, Wv, Wo, tp,
                                    xb, wqb, wkb, wvb, wob, tab);

    gemm_qkv<<<dim3(32, 24), 512, 0, stream>>>(xb, wqb, wkb, wvb, tab, Qb, Kb, Vtb);

    attn<<<dim3(64, 16), 256, 0, stream>>>(Qb, Kb, Vtb, xb);

    gemm_o<<<dim3(64, 8), 512, 0, stream>>>(xb, wob, out);
}

// Round 16
// 226.405 us; speedup vs baseline: 2.0251x; 2.0251x over previous
//
#include <hip/hip_runtime.h>

// Problem constants: B=4, S=2048, D=1024, H=16, HD=64
#define S_LEN 2048
#define NH 16
#define HDIM 64
#define DMODEL 1024

typedef __attribute__((ext_vector_type(8))) short bf16x8;
typedef __attribute__((ext_vector_type(4))) float f32x4;

__device__ __forceinline__ short f2bf(float f) {
    union { float f; unsigned u; } x; x.f = f;
    unsigned r = x.u + 0x7fffu + ((x.u >> 16) & 1u);  // round-to-nearest-even
    return (short)(r >> 16);
}

#define GLDS(g, l) __builtin_amdgcn_global_load_lds( \
    (__attribute__((address_space(1))) void*)(g),    \
    (__attribute__((address_space(3))) void*)(l), 16, 0, 0)

#define QSCALE 0.18033688011112042f   // 0.125 * log2(e)
#define FREQ_L 0.41524101186109327f   // log2(10000)/32

// ---------------------------------------------------------------- prep (one launch)
__global__ __launch_bounds__(256) void prep(const float* __restrict__ x,
                                            const float* __restrict__ wq,
                                            const float* __restrict__ wk,
                                            const float* __restrict__ wv,
                                            const float* __restrict__ wo,
                                            const int* __restrict__ tp,
                                            short* __restrict__ xb,
                                            short* __restrict__ wqb,
                                            short* __restrict__ wkb,
                                            short* __restrict__ wvb,
                                            short* __restrict__ wob,
                                            float2* __restrict__ tab) {
    int bid = blockIdx.x;
    if (bid < 8192) {
        int i = bid * 256 + threadIdx.x;
        float4 v = ((const float4*)x)[i];
        short4 o;
        o.x = f2bf(v.x); o.y = f2bf(v.y); o.z = f2bf(v.z); o.w = f2bf(v.w);
        ((short4*)xb)[i] = o;
    } else if (bid < 12288) {
        int sel = (bid - 8192) >> 10;
        const float* in = sel == 0 ? wq : sel == 1 ? wk : sel == 2 ? wv : wo;
        short* out = sel == 0 ? wqb : sel == 1 ? wkb : sel == 2 ? wvb : wob;
        int i = ((bid - 8192) & 1023) * 256 + threadIdx.x;
        float4 v = ((const float4*)in)[i];
        short4 o;
        o.x = f2bf(v.x); o.y = f2bf(v.y); o.z = f2bf(v.z); o.w = f2bf(v.w);
        ((short4*)out)[i] = o;
    } else {
        int idx = (bid - 12288) * 256 + threadIdx.x;   // < 262144
        int b = idx >> 16, s = (idx >> 5) & 2047, i = idx & 31;
        float p = (float)tp[(b << 11) + s];
        float freq = exp2f(-(float)i * FREQ_L);
        float sn, cs;
        sincosf(p * freq, &sn, &cs);
        tab[idx] = make_float2(cs, sn);
    }
}

// ---------------------------------------------------------------- fused QKV GEMM + RoPE
// Round-12 version KEPT (66.0 us, Occ 32%, FETCH 45 MB).  2-blocks/CU
// counted-vmcnt schedule: BK=32/phase (32 phases), 3 slots x 24 KB = 72 KB
// LDS; vmcnt(3) steady (never drain).  (row>>1)&3 conflict-free addressing.
// XCD grid (32,24), bm fastest.  BM=256, BN=128; 8 waves (4Mx2N).
__global__ __launch_bounds__(512) void gemm_qkv(const short* __restrict__ A,
                                                const short* __restrict__ Bq,
                                                const short* __restrict__ Bk,
                                                const short* __restrict__ Bv,
                                                const float2* __restrict__ tab,
                                                short* __restrict__ Qo,
                                                short* __restrict__ Ko,
                                                short* __restrict__ Vo) {
    constexpr int K = 1024;
    __shared__ __align__(16) short smem[3 * 12288];

    const int bm = blockIdx.x;               // 0..31  (fastest -> XCD-pinned A)
    const int sel = blockIdx.y >> 3;         // 0..2
    const int bn = blockIdx.y & 7;           // 0..7
    const short* Bm = sel == 0 ? Bq : sel == 1 ? Bk : Bv;
    short* Cb = sel == 0 ? Qo : sel == 1 ? Ko : Vo;

    const int tid = threadIdx.x;
    const int lane = tid & 63;
    const int w = tid >> 6;          // 0..7
    const int wm = w >> 1;           // 0..3  (M-waves)
    const int wn = w & 1;            // 0..1  (N-waves)
    const int quad = lane >> 4, l16 = lane & 15;

    int aoff[2], boffv;
#pragma unroll
    for (int i = 0; i < 2; i++) {
        int Lc = i * 512 + tid;
        int row = Lc >> 2;
        int gc = (Lc & 3) ^ ((row >> 1) & 3);
        aoff[i] = (bm * 256 + row) * K + gc * 8;
    }
    {
        int row = tid >> 2;
        int gc = (tid & 3) ^ ((row >> 1) & 3);
        boffv = (bn * 128 + row) * K + gc * 8;
    }

    auto stage = [&](int h, int slot) {
        char* sbase = (char*)smem + slot * 24576;
        const int kh = h * 32;
#pragma unroll
        for (int i = 0; i < 2; i++)
            GLDS(A + aoff[i] + kh, sbase + i * 8192 + w * 1024);
        GLDS(Bm + boffv + kh, sbase + 16384 + w * 1024);
    };

    f32x4 acc[4][4] = {};
    const int rsw = (quad ^ ((l16 >> 1) & 3)) * 8;

    auto compute = [&](int slot) {
        const short* sA = smem + slot * 12288;
        const short* sB = sA + 8192;
        bf16x8 af[4], bfm[4];
#pragma unroll
        for (int mi = 0; mi < 4; mi++)
            af[mi] = *(const bf16x8*)&sA[(wm * 64 + mi * 16 + l16) * 32 + rsw];
#pragma unroll
        for (int ni = 0; ni < 4; ni++)
            bfm[ni] = *(const bf16x8*)&sB[(wn * 64 + ni * 16 + l16) * 32 + rsw];
        __builtin_amdgcn_s_setprio(1);
#pragma unroll
        for (int mi = 0; mi < 4; mi++)
#pragma unroll
            for (int ni = 0; ni < 4; ni++)
                acc[mi][ni] = __builtin_amdgcn_mfma_f32_16x16x32_bf16(af[mi], bfm[ni],
                                                                      acc[mi][ni], 0, 0, 0);
        __builtin_amdgcn_s_setprio(0);
    };

    stage(0, 0); stage(1, 1);

    auto step = [&](int h, int sc, int ss) {
        asm volatile("s_waitcnt vmcnt(3)" ::: "memory");   // tile h complete
        __builtin_amdgcn_s_barrier();
        __builtin_amdgcn_sched_barrier(0);
        stage(h + 2, ss);
        compute(sc);
    };

    for (int h = 0; h < 30; h += 3) {
        step(h + 0, 0, 2);
        step(h + 1, 1, 0);
        step(h + 2, 2, 1);
    }
    asm volatile("s_waitcnt vmcnt(3)" ::: "memory");
    __builtin_amdgcn_s_barrier();
    __builtin_amdgcn_sched_barrier(0);
    compute(0);
    asm volatile("s_waitcnt vmcnt(0)" ::: "memory");
    __builtin_amdgcn_s_barrier();
    __builtin_amdgcn_sched_barrier(0);
    compute(1);

    const int gm0 = bm * 256 + wm * 64;
    const int gn0 = bn * 128 + wn * 64;

    if (sel == 2) {
        // ---- V^T -> [B][H][64][S] via LDS transpose (re-use staging LDS).
        short* T = smem;
        __syncthreads();
#pragma unroll
        for (int mi = 0; mi < 4; mi++) {
            int lmb = wm * 64 + mi * 16 + quad * 4;
#pragma unroll
            for (int ni = 0; ni < 4; ni++) {
                int ln = wn * 64 + ni * 16 + l16;
                short4 pk;
                pk.x = f2bf(acc[mi][ni][0]);
                pk.y = f2bf(acc[mi][ni][1]);
                pk.z = f2bf(acc[mi][ni][2]);
                pk.w = f2bf(acc[mi][ni][3]);
                *(short4*)&T[ln * 256 + (lmb ^ ((ln & 31) << 3))] = pk;
            }
        }
        __syncthreads();
        const int row = tid >> 2, qt = tid & 3;
        const int grow = bn * 128 + row;
        const int gb = bm >> 3;
        const int gs0 = (bm & 7) * 256;
        short* dst = Cb + (((size_t)(gb * NH + (grow >> 6)) * HDIM + (grow & 63)) * S_LEN
                           + gs0 + qt * 64);
#pragma unroll
        for (int j = 0; j < 8; j++) {
            bf16x8 v = *(const bf16x8*)&T[row * 256 +
                        ((qt * 64 + j * 8) ^ ((row & 31) << 3))];
            *(bf16x8*)(dst + j * 8) = v;
        }
    } else {
        const float qs = (sel == 0) ? QSCALE : 1.0f;
#pragma unroll
        for (int mi = 0; mi < 4; mi++)
#pragma unroll
            for (int r = 0; r < 4; r++) {
                int gm = gm0 + mi * 16 + quad * 4 + r;        // b*2048 + s
                const float2* trow = tab + (gm << 5);
                int b = gm >> 11, s = gm & 2047;
#pragma unroll
                for (int ni = 0; ni < 4; ni++) {
                    float2 cs = trow[ni * 8 + (l16 >> 1)];
                    float v = acc[mi][ni][r];
                    float prt = __shfl_xor(v, 1, 64);
                    float val = (l16 & 1) ? (prt * cs.y + v * cs.x)
                                          : (v * cs.x - prt * cs.y);
                    int gn = gn0 + ni * 16 + l16;
                    int h = gn >> 6, hd = gn & 63;
                    Cb[((b * NH + h) * S_LEN + s) * HDIM + hd] = f2bf(val * qs);
                }
            }
    }
}

// ---------------------------------------------------------------- O-projection GEMM
// Round-13 version KEPT (2-blocks/CU: BM=128/BN=128/BK=32, 48 KB LDS,
// vmcnt(2), (row>>1)&3 addressing, grid (64,8) XCD-pinned).
__global__ __launch_bounds__(512) void gemm_o(const short* __restrict__ A,
                                              const short* __restrict__ Bw,
                                              float* __restrict__ Cf) {
    constexpr int K = 1024, N = 1024;
    __shared__ __align__(16) short smem[3 * 8192];

    const int bm = blockIdx.x;       // 0..63  (fastest -> XCD-pinned A)
    const int bn = blockIdx.y;       // 0..7

    const int tid = threadIdx.x;
    const int lane = tid & 63;
    const int w = tid >> 6;          // 0..7
    const int wm = w >> 2;           // 0..1  (M-waves)
    const int wn = w & 3;            // 0..3  (N-waves)
    const int quad = lane >> 4, l16 = lane & 15;

    int aoffv, boffv;
    {
        int row = tid >> 2;
        int gc = (tid & 3) ^ ((row >> 1) & 3);
        aoffv = (bm * 128 + row) * K + gc * 8;
        boffv = (bn * 128 + row) * K + gc * 8;
    }

    auto stage = [&](int h, int slot) {
        char* sbase = (char*)smem + slot * 16384;
        const int kh = h * 32;
        GLDS(A + aoffv + kh, sbase + w * 1024);
        GLDS(Bw + boffv + kh, sbase + 8192 + w * 1024);
    };

    f32x4 acc[4][2] = {};
    const int rsw = (quad ^ ((l16 >> 1) & 3)) * 8;

    auto compute = [&](int slot) {
        const short* sA = smem + slot * 8192;
        const short* sB = sA + 4096;
        bf16x8 af[4], bfm[2];
#pragma unroll
        for (int mi = 0; mi < 4; mi++)
            af[mi] = *(const bf16x8*)&sA[(wm * 64 + mi * 16 + l16) * 32 + rsw];
#pragma unroll
        for (int ni = 0; ni < 2; ni++)
            bfm[ni] = *(const bf16x8*)&sB[(wn * 32 + ni * 16 + l16) * 32 + rsw];
        __builtin_amdgcn_s_setprio(1);
#pragma unroll
        for (int mi = 0; mi < 4; mi++)
#pragma unroll
            for (int ni = 0; ni < 2; ni++)
                acc[mi][ni] = __builtin_amdgcn_mfma_f32_16x16x32_bf16(af[mi], bfm[ni],
                                                                      acc[mi][ni], 0, 0, 0);
        __builtin_amdgcn_s_setprio(0);
    };

    stage(0, 0); stage(1, 1);

    auto step = [&](int h, int sc, int ss) {
        asm volatile("s_waitcnt vmcnt(2)" ::: "memory");
        __builtin_amdgcn_s_barrier();
        __builtin_amdgcn_sched_barrier(0);
        stage(h + 2, ss);
        compute(sc);
    };

    for (int h = 0; h < 30; h += 3) {
        step(h + 0, 0, 2);
        step(h + 1, 1, 0);
        step(h + 2, 2, 1);
    }
    asm volatile("s_waitcnt vmcnt(2)" ::: "memory");
    __builtin_amdgcn_s_barrier();
    __builtin_amdgcn_sched_barrier(0);
    compute(0);
    asm volatile("s_waitcnt vmcnt(0)" ::: "memory");
    __builtin_amdgcn_s_barrier();
    __builtin_amdgcn_sched_barrier(0);
    compute(1);

    const int gm0 = bm * 128 + wm * 64;
    const int gn0 = bn * 128 + wn * 32;
#pragma unroll
    for (int mi = 0; mi < 4; mi++)
#pragma unroll
        for (int ni = 0; ni < 2; ni++)
#pragma unroll
            for (int r = 0; r < 4; r++) {
                int gm = gm0 + mi * 16 + quad * 4 + r;
                int gn = gn0 + ni * 16 + l16;
                Cf[gm * N + gn] = acc[mi][ni][r];
            }
}

// ---------------------------------------------------------------- flash attention (causal)
// Q,K: [BH][S][64] bf16 (Q pre-scaled by 0.125*log2e), Vt: [BH][64][S] bf16,
// O: [B][S][D] bf16.  Fixed-max softmax.
// Round-16: REVERT to round-14's measured-good version.  Round-15's
// single-buffer 5-blocks/CU regressed 4.3x (284 us, FETCH 457 MB): removing
// the double-buffer exposed full HBM latency serially per tile, and 5x
// co-residency blew the K/V working set past L2 (FETCH 110 -> 457 MB).
// Lesson: never trade pipeline depth for occupancy on a latency-exposed
// loop whose footprint exceeds cache at the new occupancy.
// This version: LPT grid (64,16), Qt = 15 - blockIdx.y (longest first),
// bh = blockIdx.x fastest (XCD-pinned K/V); 2-slot K/V double-buffer +
// setprio clusters; 48 KB LDS -> 3 blocks/CU.
__global__ __launch_bounds__(256, 3) void attn(const short* __restrict__ Q,
                                               const short* __restrict__ Km,
                                               const short* __restrict__ Vt,
                                               short* __restrict__ O) {
    __shared__ __align__(16) short kbuf[2][64 * 64];   // 16 KB
    __shared__ __align__(16) short vbuf[2][64 * 64];   // 16 KB
    __shared__ __align__(16) short pbuf[4][32 * 64];   // 16 KB (per-wave private)

    const int lane = threadIdx.x & 63;
    const int w = threadIdx.x >> 6;
    const int quad = lane >> 4, l16 = lane & 15;
    const int l7 = l16 & 7;
    const int bh = blockIdx.x;         // fastest -> XCD-pinned K/V

    const short* Qg = Q  + bh * S_LEN * 64;
    const short* Kg = Km + bh * S_LEN * 64;
    const short* Vg = Vt + bh * 64 * S_LEN;
    short* myp = &pbuf[w][0];

    const int b = bh >> 4, h = bh & 15;

    bf16x8 ones;
#pragma unroll
    for (int j = 0; j < 8; j++) ones[j] = (short)0x3f80;   // bf16 1.0

    auto stage = [&](int kt, int par) {
        const short* kt_base = Kg + kt * 64 * 64;
        const short* vt_base = Vg + kt * 64;
#pragma unroll
        for (int i = 0; i < 2; ++i) {
            int ch = w * 128 + i * 64 + lane;
            int row = ch >> 3;
            int c = (ch & 7) ^ (row & 7);
            GLDS(kt_base + row * 64 + c * 8, (char*)&kbuf[par][(w * 128 + i * 64) * 8]);
        }
#pragma unroll
        for (int i = 0; i < 2; ++i) {
            int ch = w * 128 + i * 64 + lane;
            int row = ch >> 3;
            int c = (ch & 7) ^ (row & 7);
            GLDS(vt_base + row * S_LEN + c * 8, (char*)&vbuf[par][(w * 128 + i * 64) * 8]);
        }
    };

    const int Qt = 15 - blockIdx.y;    // LPT: longest blocks dispatch first
    const int nkt = 2 * Qt + 2;

    stage(0, 0);

    bf16x8 aq[2][2];
#pragma unroll
    for (int mi = 0; mi < 2; mi++) {
        int qrow = Qt * 128 + w * 32 + mi * 16 + l16;
#pragma unroll
        for (int kc = 0; kc < 2; kc++)
            aq[mi][kc] = *(const bf16x8*)&Qg[qrow * 64 + kc * 32 + quad * 8];
    }

    f32x4 oacc[2][4] = {};
    f32x4 lacc[2] = {};

    for (int kt = 0; kt < nkt; ++kt) {
        __syncthreads();   // tile (kt&1) ready; prior reads of other buffer drained
        if (kt + 1 < nkt) stage(kt + 1, (kt + 1) & 1);
        const short* kb_cur = &kbuf[kt & 1][0];
        const short* vb_cur = &vbuf[kt & 1][0];

        // ---- S = Q K^T  (independent chains: 2 mi x 4 nt)
        f32x4 sc[2][4] = {};
        __builtin_amdgcn_s_setprio(1);
#pragma unroll
        for (int nt = 0; nt < 4; nt++) {
            int raddr = (nt * 16 + l16) * 64;
#pragma unroll
            for (int kc = 0; kc < 2; kc++) {
                bf16x8 kf = *(const bf16x8*)&kb_cur[raddr + (((quad + kc * 4) ^ l7) * 8)];
                sc[0][nt] = __builtin_amdgcn_mfma_f32_16x16x32_bf16(aq[0][kc], kf, sc[0][nt], 0, 0, 0);
                sc[1][nt] = __builtin_amdgcn_mfma_f32_16x16x32_bf16(aq[1][kc], kf, sc[1][nt], 0, 0, 0);
            }
        }
        __builtin_amdgcn_s_setprio(0);
        // ---- causal mask (only last two tiles hit the diagonal)
        if (kt >= nkt - 2) {
#pragma unroll
            for (int mi = 0; mi < 2; mi++)
#pragma unroll
                for (int nt = 0; nt < 4; nt++)
#pragma unroll
                    for (int r = 0; r < 4; r++) {
                        int col = kt * 64 + nt * 16 + l16;
                        int row = Qt * 128 + w * 32 + mi * 16 + quad * 4 + r;
                        if (col > row) sc[mi][nt][r] = -__builtin_inff();
                    }
        }
        // ---- p = exp2(s); truncated bf16 store (d16_hi, zero VALU convert)
#pragma unroll
        for (int mi = 0; mi < 2; mi++)
#pragma unroll
            for (int nt = 0; nt < 4; nt++)
#pragma unroll
                for (int r = 0; r < 4; r++) {
                    float pv = __builtin_amdgcn_exp2f(sc[mi][nt][r]);
                    int q = mi * 16 + quad * 4 + r;
                    union { float f; unsigned short us[2]; } uu;
                    uu.f = pv;
                    myp[q * 64 + (((nt * 2 + (l16 >> 3)) ^ (q & 7)) * 8) + l7] =
                        (short)uu.us[1];
                }
        // ---- P: LDS -> A-frags (in-wave DS ordering; no barrier needed)
        bf16x8 ap[2][2];
#pragma unroll
        for (int mi = 0; mi < 2; mi++)
#pragma unroll
            for (int kc = 0; kc < 2; kc++)
                ap[mi][kc] = *(const bf16x8*)&myp[(mi * 16 + l16) * 64 +
                                                  (((quad + kc * 4) ^ l7) * 8)];
        // ---- O += P V ; denominator += P * ones (MFMA pipe)
        __builtin_amdgcn_s_setprio(1);
#pragma unroll
        for (int nt = 0; nt < 4; nt++) {
            int raddr = (nt * 16 + l16) * 64;
#pragma unroll
            for (int kc = 0; kc < 2; kc++) {
                bf16x8 vf = *(const bf16x8*)&vb_cur[raddr + (((quad + kc * 4) ^ l7) * 8)];
                oacc[0][nt] = __builtin_amdgcn_mfma_f32_16x16x32_bf16(ap[0][kc], vf, oacc[0][nt], 0, 0, 0);
                oacc[1][nt] = __builtin_amdgcn_mfma_f32_16x16x32_bf16(ap[1][kc], vf, oacc[1][nt], 0, 0, 0);
            }
        }
#pragma unroll
        for (int mi = 0; mi < 2; mi++) {
            lacc[mi] = __builtin_amdgcn_mfma_f32_16x16x32_bf16(ap[mi][0], ones, lacc[mi], 0, 0, 0);
            lacc[mi] = __builtin_amdgcn_mfma_f32_16x16x32_bf16(ap[mi][1], ones, lacc[mi], 0, 0, 0);
        }
        __builtin_amdgcn_s_setprio(0);
    }
    // ---- epilogue: lacc holds per-row denominators (all cols equal)
#pragma unroll
    for (int mi = 0; mi < 2; mi++)
#pragma unroll
        for (int r = 0; r < 4; r++) {
            float inv = 1.0f / lacc[mi][r];
            int srow = Qt * 128 + w * 32 + mi * 16 + quad * 4 + r;
#pragma unroll
            for (int nt = 0; nt < 4; nt++) {
                int hd = nt * 16 + l16;
                O[(b * S_LEN + srow) * DMODEL + h * HDIM + hd] = f2bf(oacc[mi][nt][r] * inv);
            }
        }
}

// ---------------------------------------------------------------- launch
extern "C" void kernel_launch(void* const* d_in, const int* in_sizes, int n_in,
                              void* d_out, int out_size, void* d_ws, size_t ws_size,
                              hipStream_t stream) {
    const float* x  = (const float*)d_in[0];
    const int*   tp = (const int*)d_in[1];
    const float* Wq = (const float*)d_in[2];
    const float* Wk = (const float*)d_in[3];
    const float* Wv = (const float*)d_in[4];
    const float* Wo = (const float*)d_in[5];
    float* out = (float*)d_out;

    char* ws = (char*)d_ws;
    const size_t MB = 1024 * 1024;
    short* xb  = (short*)(ws);             // 16 MB: x bf16 [8192][1024]; reused as o_buf
    short* wqb = (short*)(ws + 16 * MB);
    short* wkb = (short*)(ws + 18 * MB);
    short* wvb = (short*)(ws + 20 * MB);
    short* wob = (short*)(ws + 22 * MB);
    short* Qb  = (short*)(ws + 24 * MB);   // 16 MB [BH][S][64]
    short* Kb  = (short*)(ws + 40 * MB);   // 16 MB [BH][S][64]
    short* Vtb = (short*)(ws + 56 * MB);   // 16 MB [BH][64][S]
    // RoPE table (2 MB) lives in d_out: scratch until gemm_o overwrites it.
    float2* tab = (float2*)d_out;

    prep<<<13312, 256, 0, stream>>>(x, Wq, Wk, Wv, Wo, tp,
                                    xb, wqb, wkb, wvb, wob, tab);

    gemm_qkv<<<dim3(32, 24), 512, 0, stream>>>(xb, wqb, wkb, wvb, tab, Qb, Kb, Vtb);

    attn<<<dim3(64, 16), 256, 0, stream>>>(Qb, Kb, Vtb, xb);

    gemm_o<<<dim3(64, 8), 512, 0, stream>>>(xb, wob, out);
}